// Round 2
// baseline (342.022 us; speedup 1.0000x reference)
//
#include <hip/hip_runtime.h>
#include <math.h>

#define NCL 21
#define CIN 256
#define HW 4096
#define PADK 24
#define NB 2

static __device__ __forceinline__ float fastrcp(float x) {
  return __builtin_amdgcn_rcpf(x);
}

// ---------------------------------------------------------------------------
// Kernel A: f1/f2 = 1x1 conv (w @ feat + b). Block = 16 q-positions x 16
// c-chunks of 16 channels; LDS reduction across chunks. Grid 512 blocks.
#define QT 16
#define CCH 16
__global__ __launch_bounds__(256) void k_feat(
    const float* __restrict__ feat, const float* __restrict__ w1,
    const float* __restrict__ b1, const float* __restrict__ w2,
    const float* __restrict__ b2, float* __restrict__ f1T,
    float* __restrict__ f2) {
  const int t = threadIdx.x;
  const int qi = t & 15, ch = t >> 4;  // 16 chunks of 16 channels
  const int n = blockIdx.y;
  const int q = blockIdx.x * QT + qi;
  const int c0 = ch * CCH;
  const float* fp = feat + ((size_t)n * CIN + c0) * HW + q;
  float a1[NCL], a2[NCL];
#pragma unroll
  for (int k = 0; k < NCL; ++k) { a1[k] = 0.f; a2[k] = 0.f; }
#pragma unroll
  for (int cc = 0; cc < CCH; ++cc) {
    float v = fp[(size_t)cc * HW];
#pragma unroll
    for (int k = 0; k < NCL; ++k) {  // w reads thread-uniform -> s_load
      a1[k] = fmaf(v, w1[k * CIN + c0 + cc], a1[k]);
      a2[k] = fmaf(v, w2[k * CIN + c0 + cc], a2[k]);
    }
  }
  __shared__ float p1[CCH][QT][NCL];
  __shared__ float p2[CCH][QT][NCL];
#pragma unroll
  for (int k = 0; k < NCL; ++k) { p1[ch][qi][k] = a1[k]; p2[ch][qi][k] = a2[k]; }
  __syncthreads();
  for (int o = t; o < QT * NCL; o += 256) {
    int qq = o & 15, k = o >> 4;
    float s1 = b1[k], s2 = b2[k];
#pragma unroll
    for (int c = 0; c < CCH; ++c) { s1 += p1[c][qq][k]; s2 += p2[c][qq][k]; }
    int qg = blockIdx.x * QT + qq;
    f1T[((size_t)n * HW + qg) * PADK + k] = s1;
    f2[((size_t)n * NCL + k) * HW + qg] = s2;
  }
}

// ---------------------------------------------------------------------------
// Kernel B: out_temp = bilinear downsample of out (128x128 -> 64x64, align
// corners), PRE-DIVIDED by the softmax denominator l[n][p] (runs after
// k_stats). Folding 1/l here removes one load + rcp + mul from k_corr4's
// inner loop. Stored transposed+padded [n][p][24].
__global__ __launch_bounds__(256) void k_outr(
    const float* __restrict__ out, const float* __restrict__ l,
    float* __restrict__ otT) {
  int idx = blockIdx.x * 256 + threadIdx.x;
  if (idx >= NB * NCL * HW) return;
  int p = idx & (HW - 1);
  int nk = idx >> 12;
  int i = p >> 6, j = p & 63;
  double sy = (double)i * (127.0 / 63.0);
  double sx = (double)j * (127.0 / 63.0);
  int y0 = (int)sy, x0 = (int)sx;
  float wy = (float)(sy - y0), wx = (float)(sx - x0);
  int y1 = min(y0 + 1, 127), x1 = min(x0 + 1, 127);
  const float* src = out + (size_t)nk * (128 * 128);
  float v00 = src[y0 * 128 + x0], v10 = src[y1 * 128 + x0];
  float v01 = src[y0 * 128 + x1], v11 = src[y1 * 128 + x1];
  float r0 = v00 * (1.f - wy) + v10 * wy;
  float r1 = v01 * (1.f - wy) + v11 * wy;
  float val = r0 * (1.f - wx) + r1 * wx;
  int n = nk / NCL, c = nk % NCL;
  val *= fastrcp(l[(size_t)n * HW + p]);
  otT[((size_t)n * HW + p) * PADK + c] = val;
}

// ---------------------------------------------------------------------------
// Kernel T: bilinear tables for the 64->128 upsample (y/x mappings identical).
__global__ void k_tab(float* __restrict__ wtab, int* __restrict__ itab) {
  int i = threadIdx.x;
  if (i >= 128) return;
  double s = (double)i * (63.0 / 127.0);
  int i0 = (int)s;
  wtab[i] = (float)(s - i0);
  itab[i] = i0;
}

// ---------------------------------------------------------------------------
// Kernel C: l[n][p] = sum_q exp(S[n][p][q]), S = (f1.f2)/sqrt(21).
// q split 4-ways across blocks, float atomics into zeroed l. Grid 2048 blocks.
#define PT 16
__global__ __launch_bounds__(256) void k_stats(
    const float* __restrict__ f1T, const float* __restrict__ f2,
    float* __restrict__ l) {
  const int t = threadIdx.x;
  const int n = blockIdx.z;
  const int pbase = blockIdx.x * PT;
  const int q0 = blockIdx.y * 1024 + t * 4;
  const float* f2n = f2 + (size_t)n * NCL * HW;
  const float* f1n = f1T + ((size_t)n * HW + pbase) * PADK;
  const float SCALE = 1.0f / sqrtf(21.0f);
  float4 fq[NCL];
#pragma unroll
  for (int k = 0; k < NCL; ++k)
    fq[k] = *(const float4*)(f2n + (size_t)k * HW + q0);
  float sums[PT];
#pragma unroll
  for (int p = 0; p < PT; ++p) {
    const float* f1p = f1n + p * PADK;  // uniform -> s_load
    float s0 = 0.f, s1 = 0.f, s2 = 0.f, s3 = 0.f;
#pragma unroll
    for (int k = 0; k < NCL; ++k) {
      float a = f1p[k];
      s0 = fmaf(a, fq[k].x, s0);
      s1 = fmaf(a, fq[k].y, s1);
      s2 = fmaf(a, fq[k].z, s2);
      s3 = fmaf(a, fq[k].w, s3);
    }
    sums[p] = __expf(s0 * SCALE) + __expf(s1 * SCALE) + __expf(s2 * SCALE) +
              __expf(s3 * SCALE);
  }
  __shared__ float part[4][PT];
  const int wave = t >> 6, lane = t & 63;
#pragma unroll
  for (int p = 0; p < PT; ++p) {
    float s = sums[p];
    for (int off = 32; off > 0; off >>= 1) s += __shfl_xor(s, off, 64);
    if (lane == 0) part[wave][p] = s;
  }
  __syncthreads();
  if (t < PT) {
    float tot = part[0][t] + part[1][t] + part[2][t] + part[3][t];
    atomicAdd(l + (size_t)n * HW + pbase + t, tot);
  }
}

// ---------------------------------------------------------------------------
// Kernel D (v3): atomic-free partials with VECTOR-path operands.
// Round-1 lesson: block-uniform f1/ot rows compile to s_load chains; SMEM
// results need lgkmcnt(0) (unordered), K$ has no reuse here, so each p-iter
// serialized a ~500-1000 cyc stall that only high occupancy can hide.
// Fix: 4-lane groups own one q each; lane j in the group owns p===j (mod 4),
// so row reads are genuinely per-lane -> coalesced global_load_dwordx4,
// software-pipelined by the compiler via counted vmcnt. Math per (p,q) pair
// is unchanged (no redundant work); the only overhead is a 2-step shfl_xor
// butterfly over acc[21] once per thread. Grid 64 q-blocks x 16 p-blocks x 2
// = 2048 blocks (8 blocks/CU queued). p-split stays 16 so the 11 MB slabs
// still fit in out0. 1/l is pre-folded into otT by k_outr.
#define DPS 256
__global__ __launch_bounds__(256) void k_corr4(
    const float* __restrict__ f1T, const float* __restrict__ f2,
    const float* __restrict__ otT, float* __restrict__ part) {
  const int t = threadIdx.x;
  const int lane = t & 63, w = t >> 6;
  const int g = lane >> 2, j = lane & 3;
  const int n = blockIdx.z;
  const int pb = blockIdx.y;
  const int pbase = pb * DPS;
  const int q = blockIdx.x * 64 + w * 16 + g;
  const float* f2n = f2 + (size_t)n * NCL * HW;
  const float SCALE = 1.0f / sqrtf(21.0f);
  float fq[NCL];
#pragma unroll
  for (int k = 0; k < NCL; ++k) fq[k] = f2n[(size_t)k * HW + q];
  float acc[NCL];
#pragma unroll
  for (int k = 0; k < NCL; ++k) acc[k] = 0.f;
  const float* f1b = f1T + ((size_t)n * HW + pbase + j) * PADK;
  const float* otb = otT + ((size_t)n * HW + pbase + j) * PADK;
  for (int i = 0; i < DPS / 4; ++i) {
    const float4* f1r = (const float4*)(f1b + (size_t)i * 4 * PADK);
    const float4* otr = (const float4*)(otb + (size_t)i * 4 * PADK);
    float4 a0 = f1r[0], a1 = f1r[1], a2 = f1r[2], a3 = f1r[3], a4 = f1r[4];
    float a20 = ((const float*)f1r)[20];
    float4 o0 = otr[0], o1 = otr[1], o2 = otr[2], o3 = otr[3], o4 = otr[4];
    float o20 = ((const float*)otr)[20];
    // two dot chains: latency path ~11 FMA not 21
    float sa = a0.x * fq[0];
    sa = fmaf(a0.y, fq[1], sa);
    sa = fmaf(a0.z, fq[2], sa);
    sa = fmaf(a0.w, fq[3], sa);
    sa = fmaf(a1.x, fq[4], sa);
    sa = fmaf(a1.y, fq[5], sa);
    sa = fmaf(a1.z, fq[6], sa);
    sa = fmaf(a1.w, fq[7], sa);
    sa = fmaf(a2.x, fq[8], sa);
    sa = fmaf(a2.y, fq[9], sa);
    sa = fmaf(a2.z, fq[10], sa);
    float sb = a2.w * fq[11];
    sb = fmaf(a3.x, fq[12], sb);
    sb = fmaf(a3.y, fq[13], sb);
    sb = fmaf(a3.z, fq[14], sb);
    sb = fmaf(a3.w, fq[15], sb);
    sb = fmaf(a4.x, fq[16], sb);
    sb = fmaf(a4.y, fq[17], sb);
    sb = fmaf(a4.z, fq[18], sb);
    sb = fmaf(a4.w, fq[19], sb);
    sb = fmaf(a20, fq[20], sb);
    float wgt = __expf((sa + sb) * SCALE);  // 1/l already folded into otT
    acc[0] = fmaf(o0.x, wgt, acc[0]);
    acc[1] = fmaf(o0.y, wgt, acc[1]);
    acc[2] = fmaf(o0.z, wgt, acc[2]);
    acc[3] = fmaf(o0.w, wgt, acc[3]);
    acc[4] = fmaf(o1.x, wgt, acc[4]);
    acc[5] = fmaf(o1.y, wgt, acc[5]);
    acc[6] = fmaf(o1.z, wgt, acc[6]);
    acc[7] = fmaf(o1.w, wgt, acc[7]);
    acc[8] = fmaf(o2.x, wgt, acc[8]);
    acc[9] = fmaf(o2.y, wgt, acc[9]);
    acc[10] = fmaf(o2.z, wgt, acc[10]);
    acc[11] = fmaf(o2.w, wgt, acc[11]);
    acc[12] = fmaf(o3.x, wgt, acc[12]);
    acc[13] = fmaf(o3.y, wgt, acc[13]);
    acc[14] = fmaf(o3.z, wgt, acc[14]);
    acc[15] = fmaf(o3.w, wgt, acc[15]);
    acc[16] = fmaf(o4.x, wgt, acc[16]);
    acc[17] = fmaf(o4.y, wgt, acc[17]);
    acc[18] = fmaf(o4.z, wgt, acc[18]);
    acc[19] = fmaf(o4.w, wgt, acc[19]);
    acc[20] = fmaf(o20, wgt, acc[20]);
  }
  // sum the 4 p-phases within each lane group (butterfly: all lanes get sum)
#pragma unroll
  for (int k = 0; k < NCL; ++k) {
    acc[k] += __shfl_xor(acc[k], 1, 64);
    acc[k] += __shfl_xor(acc[k], 2, 64);
  }
  if (j == 0) {
    float* po = part + ((size_t)pb * NB + n) * NCL * HW + q;
#pragma unroll
    for (int c = 0; c < NCL; ++c) po[(size_t)c * HW] = acc[c];
  }
}

// ---------------------------------------------------------------------------
// Kernel D2: corr_out[idx] = sum over the 16 partial slabs. 672 blocks,
// fully coalesced strided reads; replaces the corr_out memset too.
__global__ __launch_bounds__(256) void k_reduce(
    const float* __restrict__ part, float* __restrict__ corr_out) {
  const int idx = blockIdx.x * 256 + threadIdx.x;  // NB*NCL*HW = 672*256
  const float* p = part + idx;
  float s = 0.f;
#pragma unroll
  for (int pb = 0; pb < HW / DPS; ++pb)
    s += p[(size_t)pb * (NB * NCL * HW)];
  corr_out[idx] = s;
}

// ---------------------------------------------------------------------------
// Kernel E1: unnormalized sampled rows. The min/max normalization downstream
// is invariant to the positive per-row softmax denominator, so we skip l[]
// entirely. Rows stored in the output-0 region itself: slot (n,i) is 16384
// floats; we park the 4096-row at its start (k_norm overwrites after reading).
__global__ __launch_bounds__(256) void k_rows(
    const float* __restrict__ f1T, const float* __restrict__ f2,
    const int* __restrict__ index, float* __restrict__ out0) {
  const int t = threadIdx.x;
  const int qc = blockIdx.x;  // 0..3
  const int i = blockIdx.y;
  const int n = blockIdx.z;
  int p = index[i];
  p = max(0, min(p, HW - 1));
  const float* f1p = f1T + ((size_t)n * HW + p) * PADK;  // uniform
  const float* f2n = f2 + (size_t)n * NCL * HW;
  const float SCALE = 1.0f / sqrtf(21.0f);
  const int q0 = qc * 1024 + t * 4;
  float4 fq[NCL];
#pragma unroll
  for (int k = 0; k < NCL; ++k)
    fq[k] = *(const float4*)(f2n + (size_t)k * HW + q0);
  float s0 = 0.f, s1 = 0.f, s2 = 0.f, s3 = 0.f;
#pragma unroll
  for (int k = 0; k < NCL; ++k) {
    float a = f1p[k];
    s0 = fmaf(a, fq[k].x, s0);
    s1 = fmaf(a, fq[k].y, s1);
    s2 = fmaf(a, fq[k].z, s2);
    s3 = fmaf(a, fq[k].w, s3);
  }
  float4 r = make_float4(__expf(s0 * SCALE), __expf(s1 * SCALE),
                         __expf(s2 * SCALE), __expf(s3 * SCALE));
  *(float4*)(out0 + ((size_t)n * 128 + i) * (128 * 128) + q0) = r;
}

// ---------------------------------------------------------------------------
// Kernel E2: per sampled row: load row -> bilinear upsample 64->128 (table-
// driven) -> min/max normalize -> >0.5 booleans as 1.0/0.0 (overwrites slot).
__global__ __launch_bounds__(256) void k_norm(
    const float* __restrict__ wtab, const int* __restrict__ itab,
    float* __restrict__ out0) {
  __shared__ float row[HW];
  __shared__ float redmn[4], redmx[4];
  __shared__ float wt[128];
  __shared__ int it[128];
  const int t = threadIdx.x;
  const int i = blockIdx.x;
  const int n = blockIdx.y;
  if (t < 128) { wt[t] = wtab[t]; it[t] = itab[t]; }
  float* slot = out0 + ((size_t)n * 128 + i) * (128 * 128);
#pragma unroll
  for (int j = 0; j < 4; ++j)
    *(float4*)(row + t * 4 + j * 1024) = *(const float4*)(slot + t * 4 + j * 1024);
  __syncthreads();
  float vv[64];
  float lmn = 1e30f, lmx = -1e30f;
  for (int j = 0; j < 64; ++j) {
    int pix = t + j * 256;
    int yy = pix >> 7, xx = pix & 127;
    int y0 = it[yy], x0 = it[xx];
    float wy = wt[yy], wx = wt[xx];
    int y1 = min(y0 + 1, 63), x1 = min(x0 + 1, 63);
    float r0 = row[y0 * 64 + x0] * (1.f - wy) + row[y1 * 64 + x0] * wy;
    float r1 = row[y0 * 64 + x1] * (1.f - wy) + row[y1 * 64 + x1] * wy;
    float v = r0 * (1.f - wx) + r1 * wx;
    vv[j] = v;
    lmn = fminf(lmn, v);
    lmx = fmaxf(lmx, v);
  }
  for (int off = 32; off > 0; off >>= 1) {
    lmn = fminf(lmn, __shfl_xor(lmn, off, 64));
    lmx = fmaxf(lmx, __shfl_xor(lmx, off, 64));
  }
  const int wave = t >> 6, lane = t & 63;
  if (lane == 0) { redmn[wave] = lmn; redmx[wave] = lmx; }
  __syncthreads();
  float mn = fminf(fminf(redmn[0], redmn[1]), fminf(redmn[2], redmn[3]));
  float mx = fmaxf(fmaxf(redmx[0], redmx[1]), fmaxf(redmx[2], redmx[3]));
  float rng = mx - mn;
  for (int j = 0; j < 64; ++j) {
    int pix = t + j * 256;
    float nrm = (vv[j] - mn) / rng;
    slot[pix] = (nrm > 0.5f) ? 1.0f : 0.0f;
  }
}

// ---------------------------------------------------------------------------
extern "C" void kernel_launch(void* const* d_in, const int* in_sizes, int n_in,
                              void* d_out, int out_size, void* d_ws,
                              size_t ws_size, hipStream_t stream) {
  (void)in_sizes; (void)n_in; (void)out_size; (void)ws_size;
  const float* feat = (const float*)d_in[0];
  const float* out  = (const float*)d_in[1];
  const float* w1   = (const float*)d_in[2];
  const float* b1   = (const float*)d_in[3];
  const float* w2   = (const float*)d_in[4];
  const float* b2   = (const float*)d_in[5];
  const int* index  = (const int*)d_in[6];

  float* ws   = (float*)d_ws;
  float* f1T  = ws;                                   // 2*4096*24 = 196608
  float* f2   = ws + 196608;                          // 2*21*4096 = 172032
  float* otT  = ws + 196608 + 172032;                 // 196608
  float* lbuf = ws + 196608 + 172032 + 196608;        // 8192
  float* wtab = lbuf + 8192;                          // 128
  int*   itab = (int*)(wtab + 128);                   // 128

  float* out0     = (float*)d_out;                    // 2*128*128*128
  float* corr_out = out0 + (size_t)NB * 128 * 128 * 128;  // 2*21*4096
  // partial slabs: 16 * 2 * 21 * 4096 floats = 11.0 MB, parked inside the
  // out0 region (16.8 MB) -- consumed by k_reduce before k_rows writes out0.
  float* part = out0;

  k_feat<<<dim3(HW / QT, 2), 256, 0, stream>>>(feat, w1, b1, w2, b2, f1T, f2);
  k_tab<<<dim3(1), 128, 0, stream>>>(wtab, itab);
  hipMemsetAsync(lbuf, 0, (size_t)NB * HW * sizeof(float), stream);
  k_stats<<<dim3(HW / PT, 4, 2), 256, 0, stream>>>(f1T, f2, lbuf);
  k_outr<<<dim3(672), 256, 0, stream>>>(out, lbuf, otT);  // folds 1/l into otT
  k_corr4<<<dim3(64, 16, 2), 256, 0, stream>>>(f1T, f2, otT, part);
  k_reduce<<<dim3(672), 256, 0, stream>>>(part, corr_out);
  k_rows<<<dim3(4, 128, 2), 256, 0, stream>>>(f1T, f2, index, out0);
  k_norm<<<dim3(128, 2), 256, 0, stream>>>(wtab, itab, out0);
}

// Round 3
// 250.825 us; speedup vs baseline: 1.3636x; 1.3636x over previous
//
#include <hip/hip_runtime.h>
#include <math.h>

#define NCL 21
#define CIN 256
#define HW 4096
#define PADK 24
#define NB 2

static __device__ __forceinline__ float fastrcp(float x) {
  return __builtin_amdgcn_rcpf(x);
}

// ---------------------------------------------------------------------------
// Kernel A: f1/f2 = 1x1 conv (w @ feat + b). Block = 16 q-positions x 16
// c-chunks of 16 channels; LDS reduction across chunks. Grid 512 blocks.
#define QT 16
#define CCH 16
__global__ __launch_bounds__(256) void k_feat(
    const float* __restrict__ feat, const float* __restrict__ w1,
    const float* __restrict__ b1, const float* __restrict__ w2,
    const float* __restrict__ b2, float* __restrict__ f1T,
    float* __restrict__ f2) {
  const int t = threadIdx.x;
  const int qi = t & 15, ch = t >> 4;  // 16 chunks of 16 channels
  const int n = blockIdx.y;
  const int q = blockIdx.x * QT + qi;
  const int c0 = ch * CCH;
  const float* fp = feat + ((size_t)n * CIN + c0) * HW + q;
  float a1[NCL], a2[NCL];
#pragma unroll
  for (int k = 0; k < NCL; ++k) { a1[k] = 0.f; a2[k] = 0.f; }
#pragma unroll
  for (int cc = 0; cc < CCH; ++cc) {
    float v = fp[(size_t)cc * HW];
#pragma unroll
    for (int k = 0; k < NCL; ++k) {  // w reads thread-uniform -> s_load
      a1[k] = fmaf(v, w1[k * CIN + c0 + cc], a1[k]);
      a2[k] = fmaf(v, w2[k * CIN + c0 + cc], a2[k]);
    }
  }
  __shared__ float p1[CCH][QT][NCL];
  __shared__ float p2[CCH][QT][NCL];
#pragma unroll
  for (int k = 0; k < NCL; ++k) { p1[ch][qi][k] = a1[k]; p2[ch][qi][k] = a2[k]; }
  __syncthreads();
  for (int o = t; o < QT * NCL; o += 256) {
    int qq = o & 15, k = o >> 4;
    float s1 = b1[k], s2 = b2[k];
#pragma unroll
    for (int c = 0; c < CCH; ++c) { s1 += p1[c][qq][k]; s2 += p2[c][qq][k]; }
    int qg = blockIdx.x * QT + qq;
    f1T[((size_t)n * HW + qg) * PADK + k] = s1;
    f2[((size_t)n * NCL + k) * HW + qg] = s2;
  }
}

// ---------------------------------------------------------------------------
// Kernel B: out_temp = bilinear downsample of out (128x128 -> 64x64, align
// corners), PRE-DIVIDED by the softmax denominator l[n][p] (runs after
// k_stats). Stored transposed+padded [n][p][24].
__global__ __launch_bounds__(256) void k_outr(
    const float* __restrict__ out, const float* __restrict__ l,
    float* __restrict__ otT) {
  int idx = blockIdx.x * 256 + threadIdx.x;
  if (idx >= NB * NCL * HW) return;
  int p = idx & (HW - 1);
  int nk = idx >> 12;
  int i = p >> 6, j = p & 63;
  double sy = (double)i * (127.0 / 63.0);
  double sx = (double)j * (127.0 / 63.0);
  int y0 = (int)sy, x0 = (int)sx;
  float wy = (float)(sy - y0), wx = (float)(sx - x0);
  int y1 = min(y0 + 1, 127), x1 = min(x0 + 1, 127);
  const float* src = out + (size_t)nk * (128 * 128);
  float v00 = src[y0 * 128 + x0], v10 = src[y1 * 128 + x0];
  float v01 = src[y0 * 128 + x1], v11 = src[y1 * 128 + x1];
  float r0 = v00 * (1.f - wy) + v10 * wy;
  float r1 = v01 * (1.f - wy) + v11 * wy;
  float val = r0 * (1.f - wx) + r1 * wx;
  int n = nk / NCL, c = nk % NCL;
  val *= fastrcp(l[(size_t)n * HW + p]);
  otT[((size_t)n * HW + p) * PADK + c] = val;
}

// ---------------------------------------------------------------------------
// Kernel T: bilinear tables for the 64->128 upsample (y/x mappings identical).
__global__ void k_tab(float* __restrict__ wtab, int* __restrict__ itab) {
  int i = threadIdx.x;
  if (i >= 128) return;
  double s = (double)i * (63.0 / 127.0);
  int i0 = (int)s;
  wtab[i] = (float)(s - i0);
  itab[i] = i0;
}

// ---------------------------------------------------------------------------
// Kernel C: l[n][p] = sum_q exp(S[n][p][q]), S = (f1.f2)/sqrt(21).
// q split 4-ways across blocks, float atomics into zeroed l. Grid 2048 blocks.
// v3: the 16 f1 rows are staged in LDS (ds_read returns are ORDERED -> the
// compiler emits counted lgkmcnt and pipelines), replacing the per-p s_load
// chain whose SMEM semantics force a full lgkmcnt(0) drain each iteration.
#define PT 16
__global__ __launch_bounds__(256) void k_stats(
    const float* __restrict__ f1T, const float* __restrict__ f2,
    float* __restrict__ l) {
  __shared__ float srow[PT * PADK];  // 16 rows * 24 floats = 1.5 KB
  const int t = threadIdx.x;
  const int n = blockIdx.z;
  const int pbase = blockIdx.x * PT;
  if (t < PT * PADK / 4) {
    ((float4*)srow)[t] =
        ((const float4*)(f1T + ((size_t)n * HW + pbase) * PADK))[t];
  }
  __syncthreads();
  const int q0 = blockIdx.y * 1024 + t * 4;
  const float* f2n = f2 + (size_t)n * NCL * HW;
  const float SCALE = 1.0f / sqrtf(21.0f);
  float4 fq[NCL];
#pragma unroll
  for (int k = 0; k < NCL; ++k)
    fq[k] = *(const float4*)(f2n + (size_t)k * HW + q0);
  float sums[PT];
#pragma unroll
  for (int p = 0; p < PT; ++p) {
    const float4* r1 = (const float4*)(srow + p * PADK);
    float a[21];
    *(float4*)(a + 0) = r1[0];
    *(float4*)(a + 4) = r1[1];
    *(float4*)(a + 8) = r1[2];
    *(float4*)(a + 12) = r1[3];
    *(float4*)(a + 16) = r1[4];
    a[20] = ((const float*)r1)[20];
    float s0 = 0.f, s1 = 0.f, s2 = 0.f, s3 = 0.f;
#pragma unroll
    for (int k = 0; k < NCL; ++k) {
      s0 = fmaf(a[k], fq[k].x, s0);
      s1 = fmaf(a[k], fq[k].y, s1);
      s2 = fmaf(a[k], fq[k].z, s2);
      s3 = fmaf(a[k], fq[k].w, s3);
    }
    sums[p] = __expf(s0 * SCALE) + __expf(s1 * SCALE) + __expf(s2 * SCALE) +
              __expf(s3 * SCALE);
  }
  __shared__ float part[4][PT];
  const int wave = t >> 6, lane = t & 63;
#pragma unroll
  for (int p = 0; p < PT; ++p) {
    float s = sums[p];
    for (int off = 32; off > 0; off >>= 1) s += __shfl_xor(s, off, 64);
    if (lane == 0) part[wave][p] = s;
  }
  __syncthreads();
  if (t < PT) {
    float tot = part[0][t] + part[1][t] + part[2][t] + part[3][t];
    atomicAdd(l + (size_t)n * HW + pbase + t, tot);
  }
}

// ---------------------------------------------------------------------------
// Kernel D (v4): LDS-staged rows. Lessons R0-R2: the block-uniform f1/ot row
// stream is the bottleneck in every variant -- s_load can't pipeline (SMEM
// unordered -> lgkmcnt(0) drains everything incl. prefetches), and lane-
// replicated flat loads don't get double-buffered (R2: VGPR=48, VALU 17.8%).
// Fix: stage DPS rows of f1+ot in LDS once per block (coalesced float4 global
// loads, one vmcnt drain), inner loop reads rows via broadcast ds_read_b128
// (same-address = conflict-free; DS returns in order -> compiler pipelines
// with counted lgkmcnt across the unrolled loop).
// Geometry: 24 p-blocks (DPS=171, ragged tail) x 16 q-blocks x 2 = 768 blocks
// = 3 blocks/CU = 3 waves/SIMD; LDS 2*171*24*4 = 33 KB (3x = 98 KB/CU fits);
// slabs 24 * 672 KB = 16.5 MB <= out0's 16.8 MB. 1/l pre-folded into otT.
#define PSPLIT 24
#define DPS 171
__global__ __launch_bounds__(256) void k_corr5(
    const float* __restrict__ f1T, const float* __restrict__ f2,
    const float* __restrict__ otT, float* __restrict__ part) {
  __shared__ float sf1[DPS * PADK];
  __shared__ float sot[DPS * PADK];
  const int t = threadIdx.x;
  const int n = blockIdx.z, pb = blockIdx.y;
  const int pbase = pb * DPS;
  const int pcount = min(DPS, HW - pbase);
  {
    const float4* gf = (const float4*)(f1T + ((size_t)n * HW + pbase) * PADK);
    const float4* go = (const float4*)(otT + ((size_t)n * HW + pbase) * PADK);
    float4* sa = (float4*)sf1;
    float4* sb = (float4*)sot;
    for (int i = t; i < pcount * (PADK / 4); i += 256) {
      sa[i] = gf[i];
      sb[i] = go[i];
    }
  }
  __syncthreads();
  const int q = blockIdx.x * 256 + t;
  const float* f2n = f2 + (size_t)n * NCL * HW;
  const float SCALE = 1.0f / sqrtf(21.0f);
  float fq[NCL];
#pragma unroll
  for (int k = 0; k < NCL; ++k) fq[k] = f2n[(size_t)k * HW + q];
  float acc[NCL];
#pragma unroll
  for (int k = 0; k < NCL; ++k) acc[k] = 0.f;
#pragma unroll 2
  for (int p = 0; p < pcount; ++p) {
    const float4* r1 = (const float4*)(sf1 + p * PADK);
    const float4* ro = (const float4*)(sot + p * PADK);
    float4 a0 = r1[0], a1 = r1[1], a2 = r1[2], a3 = r1[3], a4 = r1[4];
    float a20 = ((const float*)r1)[20];
    float4 o0 = ro[0], o1 = ro[1], o2 = ro[2], o3 = ro[3], o4 = ro[4];
    float o20 = ((const float*)ro)[20];
    // two dot chains: latency path ~11 FMA not 21
    float sa = a0.x * fq[0];
    sa = fmaf(a0.y, fq[1], sa);
    sa = fmaf(a0.z, fq[2], sa);
    sa = fmaf(a0.w, fq[3], sa);
    sa = fmaf(a1.x, fq[4], sa);
    sa = fmaf(a1.y, fq[5], sa);
    sa = fmaf(a1.z, fq[6], sa);
    sa = fmaf(a1.w, fq[7], sa);
    sa = fmaf(a2.x, fq[8], sa);
    sa = fmaf(a2.y, fq[9], sa);
    sa = fmaf(a2.z, fq[10], sa);
    float sb = a2.w * fq[11];
    sb = fmaf(a3.x, fq[12], sb);
    sb = fmaf(a3.y, fq[13], sb);
    sb = fmaf(a3.z, fq[14], sb);
    sb = fmaf(a3.w, fq[15], sb);
    sb = fmaf(a4.x, fq[16], sb);
    sb = fmaf(a4.y, fq[17], sb);
    sb = fmaf(a4.z, fq[18], sb);
    sb = fmaf(a4.w, fq[19], sb);
    sb = fmaf(a20, fq[20], sb);
    float wgt = __expf((sa + sb) * SCALE);  // 1/l already folded into otT
    acc[0] = fmaf(o0.x, wgt, acc[0]);
    acc[1] = fmaf(o0.y, wgt, acc[1]);
    acc[2] = fmaf(o0.z, wgt, acc[2]);
    acc[3] = fmaf(o0.w, wgt, acc[3]);
    acc[4] = fmaf(o1.x, wgt, acc[4]);
    acc[5] = fmaf(o1.y, wgt, acc[5]);
    acc[6] = fmaf(o1.z, wgt, acc[6]);
    acc[7] = fmaf(o1.w, wgt, acc[7]);
    acc[8] = fmaf(o2.x, wgt, acc[8]);
    acc[9] = fmaf(o2.y, wgt, acc[9]);
    acc[10] = fmaf(o2.z, wgt, acc[10]);
    acc[11] = fmaf(o2.w, wgt, acc[11]);
    acc[12] = fmaf(o3.x, wgt, acc[12]);
    acc[13] = fmaf(o3.y, wgt, acc[13]);
    acc[14] = fmaf(o3.z, wgt, acc[14]);
    acc[15] = fmaf(o3.w, wgt, acc[15]);
    acc[16] = fmaf(o4.x, wgt, acc[16]);
    acc[17] = fmaf(o4.y, wgt, acc[17]);
    acc[18] = fmaf(o4.z, wgt, acc[18]);
    acc[19] = fmaf(o4.w, wgt, acc[19]);
    acc[20] = fmaf(o20, wgt, acc[20]);
  }
  float* po = part + ((size_t)pb * NB + n) * NCL * HW + q;
#pragma unroll
  for (int c = 0; c < NCL; ++c) po[(size_t)c * HW] = acc[c];
}

// ---------------------------------------------------------------------------
// Kernel D2: corr_out[idx] = sum over the 24 partial slabs. 672 blocks,
// fully coalesced strided reads; replaces the corr_out memset too.
__global__ __launch_bounds__(256) void k_reduce(
    const float* __restrict__ part, float* __restrict__ corr_out) {
  const int idx = blockIdx.x * 256 + threadIdx.x;  // NB*NCL*HW = 672*256
  const float* p = part + idx;
  float s = 0.f;
#pragma unroll
  for (int pb = 0; pb < PSPLIT; ++pb)
    s += p[(size_t)pb * (NB * NCL * HW)];
  corr_out[idx] = s;
}

// ---------------------------------------------------------------------------
// Kernel E1: unnormalized sampled rows. The min/max normalization downstream
// is invariant to the positive per-row softmax denominator, so we skip l[]
// entirely. Rows stored in the output-0 region itself: slot (n,i) is 16384
// floats; we park the 4096-row at its start (k_norm overwrites after reading).
__global__ __launch_bounds__(256) void k_rows(
    const float* __restrict__ f1T, const float* __restrict__ f2,
    const int* __restrict__ index, float* __restrict__ out0) {
  const int t = threadIdx.x;
  const int qc = blockIdx.x;  // 0..3
  const int i = blockIdx.y;
  const int n = blockIdx.z;
  int p = index[i];
  p = max(0, min(p, HW - 1));
  const float* f1p = f1T + ((size_t)n * HW + p) * PADK;  // uniform
  const float* f2n = f2 + (size_t)n * NCL * HW;
  const float SCALE = 1.0f / sqrtf(21.0f);
  const int q0 = qc * 1024 + t * 4;
  float4 fq[NCL];
#pragma unroll
  for (int k = 0; k < NCL; ++k)
    fq[k] = *(const float4*)(f2n + (size_t)k * HW + q0);
  float s0 = 0.f, s1 = 0.f, s2 = 0.f, s3 = 0.f;
#pragma unroll
  for (int k = 0; k < NCL; ++k) {
    float a = f1p[k];
    s0 = fmaf(a, fq[k].x, s0);
    s1 = fmaf(a, fq[k].y, s1);
    s2 = fmaf(a, fq[k].z, s2);
    s3 = fmaf(a, fq[k].w, s3);
  }
  float4 r = make_float4(__expf(s0 * SCALE), __expf(s1 * SCALE),
                         __expf(s2 * SCALE), __expf(s3 * SCALE));
  *(float4*)(out0 + ((size_t)n * 128 + i) * (128 * 128) + q0) = r;
}

// ---------------------------------------------------------------------------
// Kernel E2: per sampled row: load row -> bilinear upsample 64->128 (table-
// driven) -> min/max normalize -> >0.5 booleans as 1.0/0.0 (overwrites slot).
__global__ __launch_bounds__(256) void k_norm(
    const float* __restrict__ wtab, const int* __restrict__ itab,
    float* __restrict__ out0) {
  __shared__ float row[HW];
  __shared__ float redmn[4], redmx[4];
  __shared__ float wt[128];
  __shared__ int it[128];
  const int t = threadIdx.x;
  const int i = blockIdx.x;
  const int n = blockIdx.y;
  if (t < 128) { wt[t] = wtab[t]; it[t] = itab[t]; }
  float* slot = out0 + ((size_t)n * 128 + i) * (128 * 128);
#pragma unroll
  for (int j = 0; j < 4; ++j)
    *(float4*)(row + t * 4 + j * 1024) = *(const float4*)(slot + t * 4 + j * 1024);
  __syncthreads();
  float vv[64];
  float lmn = 1e30f, lmx = -1e30f;
  for (int j = 0; j < 64; ++j) {
    int pix = t + j * 256;
    int yy = pix >> 7, xx = pix & 127;
    int y0 = it[yy], x0 = it[xx];
    float wy = wt[yy], wx = wt[xx];
    int y1 = min(y0 + 1, 63), x1 = min(x0 + 1, 63);
    float r0 = row[y0 * 64 + x0] * (1.f - wy) + row[y1 * 64 + x0] * wy;
    float r1 = row[y0 * 64 + x1] * (1.f - wy) + row[y1 * 64 + x1] * wy;
    float v = r0 * (1.f - wx) + r1 * wx;
    vv[j] = v;
    lmn = fminf(lmn, v);
    lmx = fmaxf(lmx, v);
  }
  for (int off = 32; off > 0; off >>= 1) {
    lmn = fminf(lmn, __shfl_xor(lmn, off, 64));
    lmx = fmaxf(lmx, __shfl_xor(lmx, off, 64));
  }
  const int wave = t >> 6, lane = t & 63;
  if (lane == 0) { redmn[wave] = lmn; redmx[wave] = lmx; }
  __syncthreads();
  float mn = fminf(fminf(redmn[0], redmn[1]), fminf(redmn[2], redmn[3]));
  float mx = fmaxf(fmaxf(redmx[0], redmx[1]), fmaxf(redmx[2], redmx[3]));
  float rng = mx - mn;
  for (int j = 0; j < 64; ++j) {
    int pix = t + j * 256;
    float nrm = (vv[j] - mn) / rng;
    slot[pix] = (nrm > 0.5f) ? 1.0f : 0.0f;
  }
}

// ---------------------------------------------------------------------------
extern "C" void kernel_launch(void* const* d_in, const int* in_sizes, int n_in,
                              void* d_out, int out_size, void* d_ws,
                              size_t ws_size, hipStream_t stream) {
  (void)in_sizes; (void)n_in; (void)out_size; (void)ws_size;
  const float* feat = (const float*)d_in[0];
  const float* out  = (const float*)d_in[1];
  const float* w1   = (const float*)d_in[2];
  const float* b1   = (const float*)d_in[3];
  const float* w2   = (const float*)d_in[4];
  const float* b2   = (const float*)d_in[5];
  const int* index  = (const int*)d_in[6];

  float* ws   = (float*)d_ws;
  float* f1T  = ws;                                   // 2*4096*24 = 196608
  float* f2   = ws + 196608;                          // 2*21*4096 = 172032
  float* otT  = ws + 196608 + 172032;                 // 196608
  float* lbuf = ws + 196608 + 172032 + 196608;        // 8192
  float* wtab = lbuf + 8192;                          // 128
  int*   itab = (int*)(wtab + 128);                   // 128

  float* out0     = (float*)d_out;                    // 2*128*128*128
  float* corr_out = out0 + (size_t)NB * 128 * 128 * 128;  // 2*21*4096
  // partial slabs: 24 * 2 * 21 * 4096 floats = 16.5 MB, parked inside the
  // out0 region (16.8 MB) -- consumed by k_reduce before k_rows writes out0.
  float* part = out0;

  k_feat<<<dim3(HW / QT, 2), 256, 0, stream>>>(feat, w1, b1, w2, b2, f1T, f2);
  k_tab<<<dim3(1), 128, 0, stream>>>(wtab, itab);
  hipMemsetAsync(lbuf, 0, (size_t)NB * HW * sizeof(float), stream);
  k_stats<<<dim3(HW / PT, 4, 2), 256, 0, stream>>>(f1T, f2, lbuf);
  k_outr<<<dim3(672), 256, 0, stream>>>(out, lbuf, otT);  // folds 1/l into otT
  k_corr5<<<dim3(16, PSPLIT, 2), 256, 0, stream>>>(f1T, f2, otT, part);
  k_reduce<<<dim3(672), 256, 0, stream>>>(part, corr_out);
  k_rows<<<dim3(4, 128, 2), 256, 0, stream>>>(f1T, f2, index, out0);
  k_norm<<<dim3(128, 2), 256, 0, stream>>>(wtab, itab, out0);
}

// Round 4
// 246.918 us; speedup vs baseline: 1.3852x; 1.0158x over previous
//
#include <hip/hip_runtime.h>
#include <math.h>

#define NCL 21
#define CIN 256
#define HW 4096
#define PADK 24
#define NB 2

static __device__ __forceinline__ float fastrcp(float x) {
  return __builtin_amdgcn_rcpf(x);
}

// ---------------------------------------------------------------------------
// Kernel A: f1/f2 = 1x1 conv (w @ feat + b). f1 rows are PRE-SCALED by
// 1/sqrt(21) (all three consumers -- stats, corr, norm -- multiply the dot by
// SCALE, so fold it into f1 once). Block = 16 q x 16 c-chunks; LDS reduction.
#define QT 16
#define CCH 16
__global__ __launch_bounds__(256) void k_feat(
    const float* __restrict__ feat, const float* __restrict__ w1,
    const float* __restrict__ b1, const float* __restrict__ w2,
    const float* __restrict__ b2, float* __restrict__ f1T,
    float* __restrict__ f2) {
  const int t = threadIdx.x;
  const int qi = t & 15, ch = t >> 4;  // 16 chunks of 16 channels
  const int n = blockIdx.y;
  const int q = blockIdx.x * QT + qi;
  const int c0 = ch * CCH;
  const float* fp = feat + ((size_t)n * CIN + c0) * HW + q;
  float a1[NCL], a2[NCL];
#pragma unroll
  for (int k = 0; k < NCL; ++k) { a1[k] = 0.f; a2[k] = 0.f; }
#pragma unroll
  for (int cc = 0; cc < CCH; ++cc) {
    float v = fp[(size_t)cc * HW];
#pragma unroll
    for (int k = 0; k < NCL; ++k) {  // w reads thread-uniform -> s_load
      a1[k] = fmaf(v, w1[k * CIN + c0 + cc], a1[k]);
      a2[k] = fmaf(v, w2[k * CIN + c0 + cc], a2[k]);
    }
  }
  __shared__ float p1[CCH][QT][NCL];
  __shared__ float p2[CCH][QT][NCL];
#pragma unroll
  for (int k = 0; k < NCL; ++k) { p1[ch][qi][k] = a1[k]; p2[ch][qi][k] = a2[k]; }
  __syncthreads();
  const float SCALE = 1.0f / sqrtf(21.0f);
  for (int o = t; o < QT * NCL; o += 256) {
    int qq = o & 15, k = o >> 4;
    float s1 = b1[k], s2 = b2[k];
#pragma unroll
    for (int c = 0; c < CCH; ++c) { s1 += p1[c][qq][k]; s2 += p2[c][qq][k]; }
    int qg = blockIdx.x * QT + qq;
    f1T[((size_t)n * HW + qg) * PADK + k] = s1 * SCALE;  // pre-scaled
    f2[((size_t)n * NCL + k) * HW + qg] = s2;
  }
}

// ---------------------------------------------------------------------------
// Kernel C (fused): per block = (16 p-rows, n). Computes l[p] = sum_q exp(S)
// over ALL 4096 q in-block (no atomics, no memset, l never hits global), then
// the k_outr epilogue for the same 16 p: bilinear-downsampled out (128->64,
// align-corners) times 1/l[p], stored transposed+padded otT[n][p][24].
#define PT 16
__global__ __launch_bounds__(256) void k_statsoutr(
    const float* __restrict__ f1T, const float* __restrict__ f2,
    const float* __restrict__ out, float* __restrict__ otT) {
  __shared__ float srow[PT * PADK];  // 16 rows * 24 floats = 1.5 KB
  __shared__ float red[4][PT];
  __shared__ float linv[PT];
  const int t = threadIdx.x;
  const int n = blockIdx.y;
  const int pbase = blockIdx.x * PT;
  if (t < PT * PADK / 4) {
    ((float4*)srow)[t] =
        ((const float4*)(f1T + ((size_t)n * HW + pbase) * PADK))[t];
  }
  __syncthreads();
  const float* f2n = f2 + (size_t)n * NCL * HW;
  float sums[PT];
#pragma unroll
  for (int p = 0; p < PT; ++p) sums[p] = 0.f;
  for (int qc = 0; qc < 4; ++qc) {
    const int q0 = qc * 1024 + t * 4;
    float4 fq[NCL];
#pragma unroll
    for (int k = 0; k < NCL; ++k)
      fq[k] = *(const float4*)(f2n + (size_t)k * HW + q0);
#pragma unroll
    for (int p = 0; p < PT; ++p) {
      const float4* r1 = (const float4*)(srow + p * PADK);
      float a[NCL];
      *(float4*)(a + 0) = r1[0];
      *(float4*)(a + 4) = r1[1];
      *(float4*)(a + 8) = r1[2];
      *(float4*)(a + 12) = r1[3];
      *(float4*)(a + 16) = r1[4];
      a[20] = ((const float*)r1)[20];
      float s0 = 0.f, s1 = 0.f, s2 = 0.f, s3 = 0.f;
#pragma unroll
      for (int k = 0; k < NCL; ++k) {
        s0 = fmaf(a[k], fq[k].x, s0);
        s1 = fmaf(a[k], fq[k].y, s1);
        s2 = fmaf(a[k], fq[k].z, s2);
        s3 = fmaf(a[k], fq[k].w, s3);
      }
      sums[p] += __expf(s0) + __expf(s1) + __expf(s2) + __expf(s3);
    }
  }
  const int wave = t >> 6, lane = t & 63;
#pragma unroll
  for (int p = 0; p < PT; ++p) {
    float s = sums[p];
    for (int off = 32; off > 0; off >>= 1) s += __shfl_xor(s, off, 64);
    if (lane == 0) red[wave][p] = s;
  }
  __syncthreads();
  if (t < PT) {
    float tot = red[0][t] + red[1][t] + red[2][t] + red[3][t];
    linv[t] = fastrcp(tot);
  }
  __syncthreads();
  // k_outr epilogue for the 16 p of this block: 16*21 = 336 outputs.
  for (int o = t; o < PT * NCL; o += 256) {
    int pl = o & 15, c = o >> 4;
    int pg = pbase + pl;
    int i = pg >> 6, j = pg & 63;
    double sy = (double)i * (127.0 / 63.0);
    double sx = (double)j * (127.0 / 63.0);
    int y0 = (int)sy, x0 = (int)sx;
    float wy = (float)(sy - y0), wx = (float)(sx - x0);
    int y1 = min(y0 + 1, 127), x1 = min(x0 + 1, 127);
    const float* src = out + ((size_t)n * NCL + c) * (128 * 128);
    float v00 = src[y0 * 128 + x0], v10 = src[y1 * 128 + x0];
    float v01 = src[y0 * 128 + x1], v11 = src[y1 * 128 + x1];
    float r0 = v00 * (1.f - wy) + v10 * wy;
    float r1 = v01 * (1.f - wy) + v11 * wy;
    float val = r0 * (1.f - wx) + r1 * wx;
    otT[((size_t)n * HW + pg) * PADK + c] = val * linv[pl];
  }
}

// ---------------------------------------------------------------------------
// Kernel D (v5): Q=4. Round-3 showed k_corr is LDS-ISSUE-bound: 12 broadcast
// ds_read per p-iter per wave serving 64 pairs = 24.6K ds/CU x ~8cyc = 82 us
// (measured 78). Each thread now owns 4 q (float4): ds/pair drops 4x ->
// LDS pipe ~20 us/CU; VALU ~25 us/SIMD becomes the limit. 64-thread blocks,
// grid 16 q x 24 p x 2 = 768 single-wave blocks = 3/CU exactly (balanced);
// LDS 33 KB x 3 = 99 KB/CU fits. unroll-2 pipelines the ds reads; VGPR ~230
// is safe (no spill till ~450, occupancy not VGPR-capped at 3 waves/CU).
#define PSPLIT 24
#define DPS 171
__global__ __launch_bounds__(64) void k_corr6(
    const float* __restrict__ f1T, const float* __restrict__ f2,
    const float* __restrict__ otT, float* __restrict__ part) {
  __shared__ float sf1[DPS * PADK];
  __shared__ float sot[DPS * PADK];
  const int t = threadIdx.x;  // 0..63
  const int n = blockIdx.z, pb = blockIdx.y;
  const int pbase = pb * DPS;
  const int pcount = min(DPS, HW - pbase);
  {
    const float4* gf = (const float4*)(f1T + ((size_t)n * HW + pbase) * PADK);
    const float4* go = (const float4*)(otT + ((size_t)n * HW + pbase) * PADK);
    float4* sa = (float4*)sf1;
    float4* sb = (float4*)sot;
    for (int i = t; i < pcount * (PADK / 4); i += 64) {
      sa[i] = gf[i];
      sb[i] = go[i];
    }
  }
  __syncthreads();
  const int q = blockIdx.x * 256 + t * 4;
  const float* f2n = f2 + (size_t)n * NCL * HW;
  float4 fq[NCL];
#pragma unroll
  for (int k = 0; k < NCL; ++k)
    fq[k] = *(const float4*)(f2n + (size_t)k * HW + q);
  float4 acc[NCL];
#pragma unroll
  for (int k = 0; k < NCL; ++k) acc[k] = make_float4(0.f, 0.f, 0.f, 0.f);
#pragma unroll 2
  for (int p = 0; p < pcount; ++p) {
    const float4* r1 = (const float4*)(sf1 + p * PADK);
    float a[NCL];
    *(float4*)(a + 0) = r1[0];
    *(float4*)(a + 4) = r1[1];
    *(float4*)(a + 8) = r1[2];
    *(float4*)(a + 12) = r1[3];
    *(float4*)(a + 16) = r1[4];
    a[20] = ((const float*)r1)[20];
    float d0 = 0.f, d1 = 0.f, d2 = 0.f, d3 = 0.f;  // 4 independent chains
#pragma unroll
    for (int k = 0; k < NCL; ++k) {
      d0 = fmaf(a[k], fq[k].x, d0);
      d1 = fmaf(a[k], fq[k].y, d1);
      d2 = fmaf(a[k], fq[k].z, d2);
      d3 = fmaf(a[k], fq[k].w, d3);
    }
    float w0 = __expf(d0), w1 = __expf(d1), w2 = __expf(d2), w3 = __expf(d3);
    const float4* ro = (const float4*)(sot + p * PADK);
    float o[NCL];
    *(float4*)(o + 0) = ro[0];
    *(float4*)(o + 4) = ro[1];
    *(float4*)(o + 8) = ro[2];
    *(float4*)(o + 12) = ro[3];
    *(float4*)(o + 16) = ro[4];
    o[20] = ((const float*)ro)[20];
#pragma unroll
    for (int k = 0; k < NCL; ++k) {
      acc[k].x = fmaf(o[k], w0, acc[k].x);
      acc[k].y = fmaf(o[k], w1, acc[k].y);
      acc[k].z = fmaf(o[k], w2, acc[k].z);
      acc[k].w = fmaf(o[k], w3, acc[k].w);
    }
  }
  float* po = part + ((size_t)pb * NB + n) * NCL * HW + q;
#pragma unroll
  for (int c = 0; c < NCL; ++c) *(float4*)(po + (size_t)c * HW) = acc[c];
}

// ---------------------------------------------------------------------------
// Kernel D2: corr_out[idx] = sum over the 24 partial slabs. 672 blocks,
// fully coalesced strided reads; replaces the corr_out memset too.
__global__ __launch_bounds__(256) void k_reduce(
    const float* __restrict__ part, float* __restrict__ corr_out) {
  const int idx = blockIdx.x * 256 + threadIdx.x;  // NB*NCL*HW = 672*256
  const float* p = part + idx;
  float s = 0.f;
#pragma unroll
  for (int pb = 0; pb < PSPLIT; ++pb)
    s += p[(size_t)pb * (NB * NCL * HW)];
  corr_out[idx] = s;
}

// ---------------------------------------------------------------------------
// Kernel E (fused): per sampled row (i, n): compute the unnormalized exp-row
// straight into LDS (k_rows fused in -- kills a launch + a 4 MB global
// roundtrip; min/max normalization is invariant to the softmax denominator),
// compute the bilinear tables in-block (k_tab fused in), upsample 64->128,
// min/max normalize, write >0.5 booleans as 1.0/0.0.
__global__ __launch_bounds__(256) void k_norm(
    const float* __restrict__ f1T, const float* __restrict__ f2,
    const int* __restrict__ index, float* __restrict__ out0) {
  __shared__ float row[HW];
  __shared__ float redmn[4], redmx[4];
  __shared__ float wt[128];
  __shared__ int it[128];
  const int t = threadIdx.x;
  const int i = blockIdx.x;
  const int n = blockIdx.y;
  // tables (was k_tab)
  if (t < 128) {
    double s = (double)t * (63.0 / 127.0);
    int i0 = (int)s;
    wt[t] = (float)(s - i0);
    it[t] = i0;
  }
  // sampled row (was k_rows): f1 row is uniform -> one-time s_loads
  int p = index[i];
  p = max(0, min(p, HW - 1));
  const float* f1p = f1T + ((size_t)n * HW + p) * PADK;
  float a[NCL];
#pragma unroll
  for (int k = 0; k < NCL; ++k) a[k] = f1p[k];
  const float* f2n = f2 + (size_t)n * NCL * HW;
  for (int qc = 0; qc < 4; ++qc) {
    const int q0 = qc * 1024 + t * 4;
    float d0 = 0.f, d1 = 0.f, d2 = 0.f, d3 = 0.f;
#pragma unroll
    for (int k = 0; k < NCL; ++k) {
      float4 f = *(const float4*)(f2n + (size_t)k * HW + q0);
      d0 = fmaf(a[k], f.x, d0);
      d1 = fmaf(a[k], f.y, d1);
      d2 = fmaf(a[k], f.z, d2);
      d3 = fmaf(a[k], f.w, d3);
    }
    *(float4*)(row + q0) =
        make_float4(__expf(d0), __expf(d1), __expf(d2), __expf(d3));
  }
  __syncthreads();
  float vv[64];
  float lmn = 1e30f, lmx = -1e30f;
  for (int j = 0; j < 64; ++j) {
    int pix = t + j * 256;
    int yy = pix >> 7, xx = pix & 127;
    int y0 = it[yy], x0 = it[xx];
    float wy = wt[yy], wx = wt[xx];
    int y1 = min(y0 + 1, 63), x1 = min(x0 + 1, 63);
    float r0 = row[y0 * 64 + x0] * (1.f - wy) + row[y1 * 64 + x0] * wy;
    float r1 = row[y0 * 64 + x1] * (1.f - wy) + row[y1 * 64 + x1] * wy;
    float v = r0 * (1.f - wx) + r1 * wx;
    vv[j] = v;
    lmn = fminf(lmn, v);
    lmx = fmaxf(lmx, v);
  }
  for (int off = 32; off > 0; off >>= 1) {
    lmn = fminf(lmn, __shfl_xor(lmn, off, 64));
    lmx = fmaxf(lmx, __shfl_xor(lmx, off, 64));
  }
  const int wave = t >> 6, lane = t & 63;
  if (lane == 0) { redmn[wave] = lmn; redmx[wave] = lmx; }
  __syncthreads();
  float mn = fminf(fminf(redmn[0], redmn[1]), fminf(redmn[2], redmn[3]));
  float mx = fmaxf(fmaxf(redmx[0], redmx[1]), fmaxf(redmx[2], redmx[3]));
  float rng = mx - mn;
  float* slot = out0 + ((size_t)n * 128 + i) * (128 * 128);
  for (int j = 0; j < 64; ++j) {
    int pix = t + j * 256;
    float nrm = (vv[j] - mn) / rng;
    slot[pix] = (nrm > 0.5f) ? 1.0f : 0.0f;
  }
}

// ---------------------------------------------------------------------------
extern "C" void kernel_launch(void* const* d_in, const int* in_sizes, int n_in,
                              void* d_out, int out_size, void* d_ws,
                              size_t ws_size, hipStream_t stream) {
  (void)in_sizes; (void)n_in; (void)out_size; (void)ws_size;
  const float* feat = (const float*)d_in[0];
  const float* out  = (const float*)d_in[1];
  const float* w1   = (const float*)d_in[2];
  const float* b1   = (const float*)d_in[3];
  const float* w2   = (const float*)d_in[4];
  const float* b2   = (const float*)d_in[5];
  const int* index  = (const int*)d_in[6];

  float* ws   = (float*)d_ws;
  float* f1T  = ws;                                   // 2*4096*24 = 196608
  float* f2   = ws + 196608;                          // 2*21*4096 = 172032
  float* otT  = ws + 196608 + 172032;                 // 196608

  float* out0     = (float*)d_out;                    // 2*128*128*128
  float* corr_out = out0 + (size_t)NB * 128 * 128 * 128;  // 2*21*4096
  // partial slabs: 24 * 2 * 21 * 4096 floats = 16.5 MB, parked inside the
  // out0 region (16.8 MB) -- consumed by k_reduce before k_norm writes out0.
  float* part = out0;

  k_feat<<<dim3(HW / QT, 2), 256, 0, stream>>>(feat, w1, b1, w2, b2, f1T, f2);
  k_statsoutr<<<dim3(HW / PT, 2), 256, 0, stream>>>(f1T, f2, out, otT);
  k_corr6<<<dim3(16, PSPLIT, 2), 64, 0, stream>>>(f1T, f2, otT, part);
  k_reduce<<<dim3(672), 256, 0, stream>>>(part, corr_out);
  k_norm<<<dim3(128, 2), 256, 0, stream>>>(f1T, f2, index, out0);
}

// Round 5
// 200.087 us; speedup vs baseline: 1.7094x; 1.2341x over previous
//
#include <hip/hip_runtime.h>
#include <math.h>

#define NCL 21
#define CIN 256
#define HW 4096
#define PADK 24
#define NB 2

static __device__ __forceinline__ float fastrcp(float x) {
  return __builtin_amdgcn_rcpf(x);
}

// ---------------------------------------------------------------------------
// Kernel A: f1/f2 = 1x1 conv (w @ feat + b). f1 rows are PRE-SCALED by
// 1/sqrt(21) (all three consumers -- stats, corr, norm -- multiply the dot by
// SCALE, so fold it into f1 once). Block = 16 q x 16 c-chunks; LDS reduction.
#define QT 16
#define CCH 16
__global__ __launch_bounds__(256) void k_feat(
    const float* __restrict__ feat, const float* __restrict__ w1,
    const float* __restrict__ b1, const float* __restrict__ w2,
    const float* __restrict__ b2, float* __restrict__ f1T,
    float* __restrict__ f2) {
  const int t = threadIdx.x;
  const int qi = t & 15, ch = t >> 4;  // 16 chunks of 16 channels
  const int n = blockIdx.y;
  const int q = blockIdx.x * QT + qi;
  const int c0 = ch * CCH;
  const float* fp = feat + ((size_t)n * CIN + c0) * HW + q;
  float a1[NCL], a2[NCL];
#pragma unroll
  for (int k = 0; k < NCL; ++k) { a1[k] = 0.f; a2[k] = 0.f; }
#pragma unroll
  for (int cc = 0; cc < CCH; ++cc) {
    float v = fp[(size_t)cc * HW];
#pragma unroll
    for (int k = 0; k < NCL; ++k) {  // w reads thread-uniform -> s_load
      a1[k] = fmaf(v, w1[k * CIN + c0 + cc], a1[k]);
      a2[k] = fmaf(v, w2[k * CIN + c0 + cc], a2[k]);
    }
  }
  __shared__ float p1[CCH][QT][NCL];
  __shared__ float p2[CCH][QT][NCL];
#pragma unroll
  for (int k = 0; k < NCL; ++k) { p1[ch][qi][k] = a1[k]; p2[ch][qi][k] = a2[k]; }
  __syncthreads();
  const float SCALE = 1.0f / sqrtf(21.0f);
  for (int o = t; o < QT * NCL; o += 256) {
    int qq = o & 15, k = o >> 4;
    float s1 = b1[k], s2 = b2[k];
#pragma unroll
    for (int c = 0; c < CCH; ++c) { s1 += p1[c][qq][k]; s2 += p2[c][qq][k]; }
    int qg = blockIdx.x * QT + qq;
    f1T[((size_t)n * HW + qg) * PADK + k] = s1 * SCALE;  // pre-scaled
    f2[((size_t)n * NCL + k) * HW + qg] = s2;
  }
}

// ---------------------------------------------------------------------------
// Kernel C (fused, v2): per block = (8 p-rows, n), all 4096 q in-block (no
// atomics, l never hits global), then the k_outr epilogue for the same 8 p.
// Round-4 lesson: holding fq[21]xfloat4 + sums[16] + a[21] live = VGPR 232 =
// 2 waves/SIMD = 30% VALU duty. Restructure: dot split over k-groups of 4;
// live set = dp[8]xfloat4 (32) + one fq group (16) + sums[8] -> ~110 VGPR ->
// 4 waves/SIMD. Same ds/FMA/load counts; group loads hide under the previous
// group's 128-FMA p-loop. Grid 512x2 = 1024 blocks = 4 blocks/CU.
#define PT 8
__global__ __launch_bounds__(256) void k_statsoutr(
    const float* __restrict__ f1T, const float* __restrict__ f2,
    const float* __restrict__ out, float* __restrict__ otT) {
  __shared__ float srow[PT * PADK];  // 8 rows * 24 floats = 768 B
  __shared__ float red[4][PT];
  __shared__ float linv[PT];
  const int t = threadIdx.x;
  const int n = blockIdx.y;
  const int pbase = blockIdx.x * PT;
  if (t < PT * PADK / 4) {
    ((float4*)srow)[t] =
        ((const float4*)(f1T + ((size_t)n * HW + pbase) * PADK))[t];
  }
  __syncthreads();
  const float* f2n = f2 + (size_t)n * NCL * HW;
  float sums[PT];
#pragma unroll
  for (int p = 0; p < PT; ++p) sums[p] = 0.f;
  for (int qc = 0; qc < 4; ++qc) {
    const int q0 = qc * 1024 + t * 4;
    float4 dp[PT];  // dot partials: 32 VGPR
#pragma unroll
    for (int p = 0; p < PT; ++p) dp[p] = make_float4(0.f, 0.f, 0.f, 0.f);
#pragma unroll
    for (int g = 0; g < 5; ++g) {  // k = 4g .. 4g+3
      float4 fg0 = *(const float4*)(f2n + (size_t)(4 * g + 0) * HW + q0);
      float4 fg1 = *(const float4*)(f2n + (size_t)(4 * g + 1) * HW + q0);
      float4 fg2 = *(const float4*)(f2n + (size_t)(4 * g + 2) * HW + q0);
      float4 fg3 = *(const float4*)(f2n + (size_t)(4 * g + 3) * HW + q0);
#pragma unroll
      for (int p = 0; p < PT; ++p) {
        float4 ag = *(const float4*)(srow + p * PADK + 4 * g);
        dp[p].x = fmaf(ag.x, fg0.x, dp[p].x);
        dp[p].y = fmaf(ag.x, fg0.y, dp[p].y);
        dp[p].z = fmaf(ag.x, fg0.z, dp[p].z);
        dp[p].w = fmaf(ag.x, fg0.w, dp[p].w);
        dp[p].x = fmaf(ag.y, fg1.x, dp[p].x);
        dp[p].y = fmaf(ag.y, fg1.y, dp[p].y);
        dp[p].z = fmaf(ag.y, fg1.z, dp[p].z);
        dp[p].w = fmaf(ag.y, fg1.w, dp[p].w);
        dp[p].x = fmaf(ag.z, fg2.x, dp[p].x);
        dp[p].y = fmaf(ag.z, fg2.y, dp[p].y);
        dp[p].z = fmaf(ag.z, fg2.z, dp[p].z);
        dp[p].w = fmaf(ag.z, fg2.w, dp[p].w);
        dp[p].x = fmaf(ag.w, fg3.x, dp[p].x);
        dp[p].y = fmaf(ag.w, fg3.y, dp[p].y);
        dp[p].z = fmaf(ag.w, fg3.z, dp[p].z);
        dp[p].w = fmaf(ag.w, fg3.w, dp[p].w);
      }
    }
    {  // k = 20 tail
      float4 f20 = *(const float4*)(f2n + (size_t)20 * HW + q0);
#pragma unroll
      for (int p = 0; p < PT; ++p) {
        float a20 = srow[p * PADK + 20];
        dp[p].x = fmaf(a20, f20.x, dp[p].x);
        dp[p].y = fmaf(a20, f20.y, dp[p].y);
        dp[p].z = fmaf(a20, f20.z, dp[p].z);
        dp[p].w = fmaf(a20, f20.w, dp[p].w);
      }
    }
#pragma unroll
    for (int p = 0; p < PT; ++p)
      sums[p] += __expf(dp[p].x) + __expf(dp[p].y) + __expf(dp[p].z) +
                 __expf(dp[p].w);
  }
  const int wave = t >> 6, lane = t & 63;
#pragma unroll
  for (int p = 0; p < PT; ++p) {
    float s = sums[p];
    for (int off = 32; off > 0; off >>= 1) s += __shfl_xor(s, off, 64);
    if (lane == 0) red[wave][p] = s;
  }
  __syncthreads();
  if (t < PT) {
    float tot = red[0][t] + red[1][t] + red[2][t] + red[3][t];
    linv[t] = fastrcp(tot);
  }
  __syncthreads();
  // k_outr epilogue for the 8 p of this block: 8*21 = 168 outputs.
  for (int o = t; o < PT * NCL; o += 256) {
    int pl = o & 7, c = o >> 3;
    int pg = pbase + pl;
    int i = pg >> 6, j = pg & 63;
    double sy = (double)i * (127.0 / 63.0);
    double sx = (double)j * (127.0 / 63.0);
    int y0 = (int)sy, x0 = (int)sx;
    float wy = (float)(sy - y0), wx = (float)(sx - x0);
    int y1 = min(y0 + 1, 127), x1 = min(x0 + 1, 127);
    const float* src = out + ((size_t)n * NCL + c) * (128 * 128);
    float v00 = src[y0 * 128 + x0], v10 = src[y1 * 128 + x0];
    float v01 = src[y0 * 128 + x1], v11 = src[y1 * 128 + x1];
    float r0 = v00 * (1.f - wy) + v10 * wy;
    float r1 = v01 * (1.f - wy) + v11 * wy;
    float val = r0 * (1.f - wx) + r1 * wx;
    otT[((size_t)n * HW + pg) * PADK + c] = val * linv[pl];
  }
}

// ---------------------------------------------------------------------------
// Kernel D (v6): Q=4 LDS-amortized (round-4 win) + 2 waves/block splitting p
// WITHIN the block. Round-4's 768 single-wave blocks = 0.75 waves/SIMD left
// the ~27 us/wave VALU minimum fully exposed. Two waves share the same LDS
// tiles (wave0 p<86, wave1 p>=86) -> 1536 waves = 1.5/SIMD, LDS unchanged
// 33 KB. Accumulators combined via the then-dead sf1 buffer (one-time).
#define PSPLIT 24
#define DPS 171
__global__ __launch_bounds__(128) void k_corr6(
    const float* __restrict__ f1T, const float* __restrict__ f2,
    const float* __restrict__ otT, float* __restrict__ part) {
  __shared__ float smem[2 * DPS * PADK];  // 32.8 KB: sf1 | sot
  float* sf1 = smem;
  float* sot = smem + DPS * PADK;
  const int t = threadIdx.x;  // 0..127
  const int lane = t & 63, wid = t >> 6;
  const int n = blockIdx.z, pb = blockIdx.y;
  const int pbase = pb * DPS;
  const int pcount = min(DPS, HW - pbase);
  {
    const float4* gf = (const float4*)(f1T + ((size_t)n * HW + pbase) * PADK);
    const float4* go = (const float4*)(otT + ((size_t)n * HW + pbase) * PADK);
    float4* sa = (float4*)sf1;
    float4* sb = (float4*)sot;
    for (int i = t; i < pcount * (PADK / 4); i += 128) {
      sa[i] = gf[i];
      sb[i] = go[i];
    }
  }
  __syncthreads();
  const int q = blockIdx.x * 256 + lane * 4;
  const float* f2n = f2 + (size_t)n * NCL * HW;
  float4 fq[NCL];
#pragma unroll
  for (int k = 0; k < NCL; ++k)
    fq[k] = *(const float4*)(f2n + (size_t)k * HW + q);
  float4 acc[NCL];
#pragma unroll
  for (int k = 0; k < NCL; ++k) acc[k] = make_float4(0.f, 0.f, 0.f, 0.f);
  const int pmid = min(86, pcount);
  const int plo = wid ? pmid : 0;
  const int phi = wid ? pcount : pmid;
#pragma unroll 2
  for (int p = plo; p < phi; ++p) {
    const float4* r1 = (const float4*)(sf1 + p * PADK);
    float a[NCL];
    *(float4*)(a + 0) = r1[0];
    *(float4*)(a + 4) = r1[1];
    *(float4*)(a + 8) = r1[2];
    *(float4*)(a + 12) = r1[3];
    *(float4*)(a + 16) = r1[4];
    a[20] = ((const float*)r1)[20];
    float d0 = 0.f, d1 = 0.f, d2 = 0.f, d3 = 0.f;  // 4 independent chains
#pragma unroll
    for (int k = 0; k < NCL; ++k) {
      d0 = fmaf(a[k], fq[k].x, d0);
      d1 = fmaf(a[k], fq[k].y, d1);
      d2 = fmaf(a[k], fq[k].z, d2);
      d3 = fmaf(a[k], fq[k].w, d3);
    }
    float w0 = __expf(d0), w1 = __expf(d1), w2 = __expf(d2), w3 = __expf(d3);
    const float4* ro = (const float4*)(sot + p * PADK);
    float o[NCL];
    *(float4*)(o + 0) = ro[0];
    *(float4*)(o + 4) = ro[1];
    *(float4*)(o + 8) = ro[2];
    *(float4*)(o + 12) = ro[3];
    *(float4*)(o + 16) = ro[4];
    o[20] = ((const float*)ro)[20];
#pragma unroll
    for (int k = 0; k < NCL; ++k) {
      acc[k].x = fmaf(o[k], w0, acc[k].x);
      acc[k].y = fmaf(o[k], w1, acc[k].y);
      acc[k].z = fmaf(o[k], w2, acc[k].z);
      acc[k].w = fmaf(o[k], w3, acc[k].w);
    }
  }
  __syncthreads();  // all ds reads of sf1/sot done; safe to reuse smem
  float4* sacc = (float4*)smem;  // 21*64 float4 = 21.5 KB (fits in smem)
  if (wid == 0) {
#pragma unroll
    for (int c = 0; c < NCL; ++c) sacc[c * 64 + lane] = acc[c];
  }
  __syncthreads();
  if (wid == 1) {
    float* po = part + ((size_t)pb * NB + n) * NCL * HW + q;
#pragma unroll
    for (int c = 0; c < NCL; ++c) {
      float4 v = sacc[c * 64 + lane];
      v.x += acc[c].x;
      v.y += acc[c].y;
      v.z += acc[c].z;
      v.w += acc[c].w;
      *(float4*)(po + (size_t)c * HW) = v;
    }
  }
}

// ---------------------------------------------------------------------------
// Kernel D2: corr_out[idx] = sum over the 24 partial slabs. 672 blocks,
// fully coalesced strided reads; replaces the corr_out memset too.
__global__ __launch_bounds__(256) void k_reduce(
    const float* __restrict__ part, float* __restrict__ corr_out) {
  const int idx = blockIdx.x * 256 + threadIdx.x;  // NB*NCL*HW = 672*256
  const float* p = part + idx;
  float s = 0.f;
#pragma unroll
  for (int pb = 0; pb < PSPLIT; ++pb)
    s += p[(size_t)pb * (NB * NCL * HW)];
  corr_out[idx] = s;
}

// ---------------------------------------------------------------------------
// Kernel E (fused): per sampled row (i, n): compute the unnormalized exp-row
// straight into LDS (min/max normalization is invariant to the softmax
// denominator), bilinear tables in-block, upsample 64->128, min/max
// normalize, write >0.5 booleans as 1.0/0.0.
__global__ __launch_bounds__(256) void k_norm(
    const float* __restrict__ f1T, const float* __restrict__ f2,
    const int* __restrict__ index, float* __restrict__ out0) {
  __shared__ float row[HW];
  __shared__ float redmn[4], redmx[4];
  __shared__ float wt[128];
  __shared__ int it[128];
  const int t = threadIdx.x;
  const int i = blockIdx.x;
  const int n = blockIdx.y;
  if (t < 128) {
    double s = (double)t * (63.0 / 127.0);
    int i0 = (int)s;
    wt[t] = (float)(s - i0);
    it[t] = i0;
  }
  int p = index[i];
  p = max(0, min(p, HW - 1));
  const float* f1p = f1T + ((size_t)n * HW + p) * PADK;
  float a[NCL];
#pragma unroll
  for (int k = 0; k < NCL; ++k) a[k] = f1p[k];
  const float* f2n = f2 + (size_t)n * NCL * HW;
  for (int qc = 0; qc < 4; ++qc) {
    const int q0 = qc * 1024 + t * 4;
    float d0 = 0.f, d1 = 0.f, d2 = 0.f, d3 = 0.f;
#pragma unroll
    for (int k = 0; k < NCL; ++k) {
      float4 f = *(const float4*)(f2n + (size_t)k * HW + q0);
      d0 = fmaf(a[k], f.x, d0);
      d1 = fmaf(a[k], f.y, d1);
      d2 = fmaf(a[k], f.z, d2);
      d3 = fmaf(a[k], f.w, d3);
    }
    *(float4*)(row + q0) =
        make_float4(__expf(d0), __expf(d1), __expf(d2), __expf(d3));
  }
  __syncthreads();
  float vv[64];
  float lmn = 1e30f, lmx = -1e30f;
  for (int j = 0; j < 64; ++j) {
    int pix = t + j * 256;
    int yy = pix >> 7, xx = pix & 127;
    int y0 = it[yy], x0 = it[xx];
    float wy = wt[yy], wx = wt[xx];
    int y1 = min(y0 + 1, 63), x1 = min(x0 + 1, 63);
    float r0 = row[y0 * 64 + x0] * (1.f - wy) + row[y1 * 64 + x0] * wy;
    float r1 = row[y0 * 64 + x1] * (1.f - wy) + row[y1 * 64 + x1] * wy;
    float v = r0 * (1.f - wx) + r1 * wx;
    vv[j] = v;
    lmn = fminf(lmn, v);
    lmx = fmaxf(lmx, v);
  }
  for (int off = 32; off > 0; off >>= 1) {
    lmn = fminf(lmn, __shfl_xor(lmn, off, 64));
    lmx = fmaxf(lmx, __shfl_xor(lmx, off, 64));
  }
  const int wave = t >> 6, lane = t & 63;
  if (lane == 0) { redmn[wave] = lmn; redmx[wave] = lmx; }
  __syncthreads();
  float mn = fminf(fminf(redmn[0], redmn[1]), fminf(redmn[2], redmn[3]));
  float mx = fmaxf(fmaxf(redmx[0], redmx[1]), fmaxf(redmx[2], redmx[3]));
  float rng = mx - mn;
  float* slot = out0 + ((size_t)n * 128 + i) * (128 * 128);
  for (int j = 0; j < 64; ++j) {
    int pix = t + j * 256;
    float nrm = (vv[j] - mn) / rng;
    slot[pix] = (nrm > 0.5f) ? 1.0f : 0.0f;
  }
}

// ---------------------------------------------------------------------------
extern "C" void kernel_launch(void* const* d_in, const int* in_sizes, int n_in,
                              void* d_out, int out_size, void* d_ws,
                              size_t ws_size, hipStream_t stream) {
  (void)in_sizes; (void)n_in; (void)out_size; (void)ws_size;
  const float* feat = (const float*)d_in[0];
  const float* out  = (const float*)d_in[1];
  const float* w1   = (const float*)d_in[2];
  const float* b1   = (const float*)d_in[3];
  const float* w2   = (const float*)d_in[4];
  const float* b2   = (const float*)d_in[5];
  const int* index  = (const int*)d_in[6];

  float* ws   = (float*)d_ws;
  float* f1T  = ws;                                   // 2*4096*24 = 196608
  float* f2   = ws + 196608;                          // 2*21*4096 = 172032
  float* otT  = ws + 196608 + 172032;                 // 196608

  float* out0     = (float*)d_out;                    // 2*128*128*128
  float* corr_out = out0 + (size_t)NB * 128 * 128 * 128;  // 2*21*4096
  // partial slabs: 24 * 2 * 21 * 4096 floats = 16.5 MB, parked inside the
  // out0 region (16.8 MB) -- consumed by k_reduce before k_norm writes out0.
  float* part = out0;

  k_feat<<<dim3(HW / QT, 2), 256, 0, stream>>>(feat, w1, b1, w2, b2, f1T, f2);
  k_statsoutr<<<dim3(HW / PT, 2), 256, 0, stream>>>(f1T, f2, out, otT);
  k_corr6<<<dim3(16, PSPLIT, 2), 128, 0, stream>>>(f1T, f2, otT, part);
  k_reduce<<<dim3(672), 256, 0, stream>>>(part, corr_out);
  k_norm<<<dim3(128, 2), 256, 0, stream>>>(f1T, f2, index, out0);
}